// Round 1
// baseline (3634.381 us; speedup 1.0000x reference)
//
#include <hip/hip_runtime.h>
#include <hip/hip_bf16.h>
#include <stdint.h>

#define N_NODES 100000
#define N_EDGES 6400000

// ---------------------------------------------------------------------------
// Detect index width of edge_index on device. If the buffer is int64, the
// high 32-bit word of every element is 0 (values < 100000). If int32, odd
// int32 positions are random node ids (nonzero w.p. 1 - 1e-5 each).
// flag = 1 -> int64, flag = 0 -> int32. Deterministic for a given dataset.
__global__ void k_detect(const unsigned* ei, int* flag) {
  __shared__ int s_any;
  if (threadIdx.x == 0) s_any = 0;
  __syncthreads();
  int local = 0;
  for (int i = threadIdx.x; i < 4096; i += blockDim.x)
    if (ei[2 * i + 1] != 0u) local = 1;
  if (local) atomicOr(&s_any, 1);
  __syncthreads();
  if (threadIdx.x == 0) *flag = (s_any ? 0 : 1);
}

// ---------------------------------------------------------------------------
// Degree of dst (self-loop added later analytically).
__global__ void k_deg(const void* __restrict__ ei, const int* __restrict__ flag,
                      float* __restrict__ deg) {
  int e = blockIdx.x * blockDim.x + threadIdx.x;
  if (e >= N_EDGES) return;
  int dst;
  if (*flag) dst = (int)((const long long*)ei)[(size_t)N_EDGES + e];
  else       dst = ((const int*)ei)[(size_t)N_EDGES + e];
  if ((unsigned)dst < N_NODES) atomicAdd(&deg[dst], 1.0f);
}

// dinv[i] = rsqrt(deg[i] + 1)  (self-loop), one Newton refinement.
__global__ void k_dinv(float* __restrict__ deg) {
  int i = blockIdx.x * blockDim.x + threadIdx.x;
  if (i >= N_NODES) return;
  float d = deg[i] + 1.0f;
  float y = rsqrtf(d);
  y = y * (1.5f - 0.5f * d * y * y);
  deg[i] = y;  // in-place: deg becomes dinv
}

// ---------------------------------------------------------------------------
// h1_lin = x @ W1   (x: [N,128], W1: [128,4]).  One wave per node.
__global__ __launch_bounds__(256) void k_mm1(const float* __restrict__ x,
                                             const float* __restrict__ W1,
                                             float* __restrict__ h1) {
  int gid = blockIdx.x * blockDim.x + threadIdx.x;
  int node = gid >> 6;
  int lane = threadIdx.x & 63;
  if (node >= N_NODES) return;
  float2 v = ((const float2*)x)[(size_t)node * 64 + lane];  // rows 2*lane, 2*lane+1
  float4 w0 = ((const float4*)W1)[2 * lane];
  float4 w1 = ((const float4*)W1)[2 * lane + 1];
  float a0 = v.x * w0.x + v.y * w1.x;
  float a1 = v.x * w0.y + v.y * w1.y;
  float a2 = v.x * w0.z + v.y * w1.z;
  float a3 = v.x * w0.w + v.y * w1.w;
#pragma unroll
  for (int off = 32; off > 0; off >>= 1) {
    a0 += __shfl_down(a0, off);
    a1 += __shfl_down(a1, off);
    a2 += __shfl_down(a2, off);
    a3 += __shfl_down(a3, off);
  }
  if (lane == 0) ((float4*)h1)[node] = make_float4(a0, a1, a2, a3);
}

// ---------------------------------------------------------------------------
// Edge aggregation: agg[dst] += h[src] * dinv[src]*dinv[dst].  F = 4 or 2.
template <int F>
__global__ void k_agg(const void* __restrict__ ei, const int* __restrict__ flag,
                      const float* __restrict__ dinv, const float* __restrict__ h,
                      float* __restrict__ agg) {
  int e = blockIdx.x * blockDim.x + threadIdx.x;
  if (e >= N_EDGES) return;
  int src, dst;
  if (*flag) {
    const long long* p = (const long long*)ei;
    src = (int)p[e];
    dst = (int)p[(size_t)N_EDGES + e];
  } else {
    const int* p = (const int*)ei;
    src = p[e];
    dst = p[(size_t)N_EDGES + e];
  }
  if ((unsigned)src >= N_NODES || (unsigned)dst >= N_NODES) return;
  float w = dinv[src] * dinv[dst];
  if (F == 4) {
    float4 v = ((const float4*)h)[src];
    atomicAdd(&agg[4 * dst + 0], v.x * w);
    atomicAdd(&agg[4 * dst + 1], v.y * w);
    atomicAdd(&agg[4 * dst + 2], v.z * w);
    atomicAdd(&agg[4 * dst + 3], v.w * w);
  } else {
    float2 v = ((const float2*)h)[src];
    atomicAdd(&agg[2 * dst + 0], v.x * w);
    atomicAdd(&agg[2 * dst + 1], v.y * w);
  }
}

// ---------------------------------------------------------------------------
// Layer-2 fused epilogue+matmul: hin = tanh(ag1 + dinv^2*h1 + b1); h2 = hin@W2.
__global__ void k_mm2(const float* __restrict__ ag1, const float* __restrict__ h1,
                      const float* __restrict__ dinv, const float* __restrict__ W2,
                      const float* __restrict__ b1, float* __restrict__ h2) {
  int i = blockIdx.x * blockDim.x + threadIdx.x;
  if (i >= N_NODES) return;
  float di = dinv[i];
  float d2 = di * di;
  float4 a = ((const float4*)ag1)[i];
  float4 hl = ((const float4*)h1)[i];
  float t0 = tanhf(a.x + d2 * hl.x + b1[0]);
  float t1 = tanhf(a.y + d2 * hl.y + b1[1]);
  float t2 = tanhf(a.z + d2 * hl.z + b1[2]);
  float t3 = tanhf(a.w + d2 * hl.w + b1[3]);
  float4 r;
  r.x = t0 * W2[0] + t1 * W2[4] + t2 * W2[8]  + t3 * W2[12];
  r.y = t0 * W2[1] + t1 * W2[5] + t2 * W2[9]  + t3 * W2[13];
  r.z = t0 * W2[2] + t1 * W2[6] + t2 * W2[10] + t3 * W2[14];
  r.w = t0 * W2[3] + t1 * W2[7] + t2 * W2[11] + t3 * W2[15];
  ((float4*)h2)[i] = r;
}

// Layer-3: hin = tanh(ag2 + dinv^2*h2 + b2); h3 = hin@W3  (W3: [4,2]).
__global__ void k_mm3(const float* __restrict__ ag2, const float* __restrict__ h2,
                      const float* __restrict__ dinv, const float* __restrict__ W3,
                      const float* __restrict__ b2, float* __restrict__ h3) {
  int i = blockIdx.x * blockDim.x + threadIdx.x;
  if (i >= N_NODES) return;
  float di = dinv[i];
  float d2 = di * di;
  float4 a = ((const float4*)ag2)[i];
  float4 hl = ((const float4*)h2)[i];
  float t0 = tanhf(a.x + d2 * hl.x + b2[0]);
  float t1 = tanhf(a.y + d2 * hl.y + b2[1]);
  float t2 = tanhf(a.z + d2 * hl.z + b2[2]);
  float t3 = tanhf(a.w + d2 * hl.w + b2[3]);
  float2 r;
  r.x = t0 * W3[0] + t1 * W3[2] + t2 * W3[4] + t3 * W3[6];
  r.y = t0 * W3[1] + t1 * W3[3] + t2 * W3[5] + t3 * W3[7];
  ((float2*)h3)[i] = r;
}

// Final: h = tanh(ag3 + dinv^2*h3 + b3); out = h@Wc + bc.  Writes both outputs.
__global__ void k_out(const float* __restrict__ ag3, const float* __restrict__ h3,
                      const float* __restrict__ dinv, const float* __restrict__ Wc,
                      const float* __restrict__ bc, const float* __restrict__ b3,
                      float* __restrict__ out) {
  int i = blockIdx.x * blockDim.x + threadIdx.x;
  if (i >= N_NODES) return;
  float di = dinv[i];
  float d2 = di * di;
  float2 a = ((const float2*)ag3)[i];
  float2 hl = ((const float2*)h3)[i];
  float t0 = tanhf(a.x + d2 * hl.x + b3[0]);
  float t1 = tanhf(a.y + d2 * hl.y + b3[1]);
#pragma unroll
  for (int c = 0; c < 10; ++c)
    out[(size_t)i * 10 + c] = t0 * Wc[c] + t1 * Wc[10 + c] + bc[c];
  // second output: final hidden h [N,2] after the logits chunk
  out[1000000 + 2 * i + 0] = t0;
  out[1000000 + 2 * i + 1] = t1;
}

// ---------------------------------------------------------------------------
extern "C" void kernel_launch(void* const* d_in, const int* in_sizes, int n_in,
                              void* d_out, int out_size, void* d_ws, size_t ws_size,
                              hipStream_t stream) {
  const float* x  = (const float*)d_in[0];
  const void*  ei = d_in[1];
  const float* W1 = (const float*)d_in[2];
  const float* b1 = (const float*)d_in[3];
  const float* W2 = (const float*)d_in[4];
  const float* b2 = (const float*)d_in[5];
  const float* W3 = (const float*)d_in[6];
  const float* b3 = (const float*)d_in[7];
  const float* Wc = (const float*)d_in[8];
  const float* bc = (const float*)d_in[9];
  float* out = (float*)d_out;

  const size_t N = N_NODES;
  float* base = (float*)d_ws;
  float* deg = base;             // N floats (becomes dinv in-place)
  float* ag1 = base + N;         // 4N
  float* ag2 = base + 5 * N;     // 4N
  float* ag3 = base + 9 * N;     // 2N
  float* h1  = base + 11 * N;    // 4N
  float* h2  = base + 15 * N;    // 4N
  float* h3  = base + 19 * N;    // 2N
  int* flag  = (int*)(base + 21 * N);

  // zero deg + all agg buffers (ws is re-poisoned before every launch)
  hipMemsetAsync(deg, 0, 11 * N * sizeof(float), stream);

  k_detect<<<1, 256, 0, stream>>>((const unsigned*)ei, flag);
  k_deg<<<N_EDGES / 256, 256, 0, stream>>>(ei, flag, deg);
  k_dinv<<<(N_NODES + 255) / 256, 256, 0, stream>>>(deg);
  k_mm1<<<(N_NODES * 64) / 256, 256, 0, stream>>>(x, W1, h1);
  k_agg<4><<<N_EDGES / 256, 256, 0, stream>>>(ei, flag, deg, h1, ag1);
  k_mm2<<<(N_NODES + 255) / 256, 256, 0, stream>>>(ag1, h1, deg, W2, b1, h2);
  k_agg<4><<<N_EDGES / 256, 256, 0, stream>>>(ei, flag, deg, h2, ag2);
  k_mm3<<<(N_NODES + 255) / 256, 256, 0, stream>>>(ag2, h2, deg, W3, b2, h3);
  k_agg<2><<<N_EDGES / 256, 256, 0, stream>>>(ei, flag, deg, h3, ag3);
  k_out<<<(N_NODES + 255) / 256, 256, 0, stream>>>(ag3, h3, deg, Wc, bc, b3, out);
}

// Round 2
// 802.660 us; speedup vs baseline: 4.5279x; 4.5279x over previous
//
#include <hip/hip_runtime.h>
#include <hip/hip_bf16.h>
#include <stdint.h>

#define N_NODES 100000
#define N_EDGES 6400000

#define SCAN_BLOCK 256
#define SCAN_ITEMS 4
#define SCAN_CHUNK (SCAN_BLOCK * SCAN_ITEMS)                  // 1024
#define N_SCAN_BLOCKS ((N_NODES + SCAN_CHUNK - 1) / SCAN_CHUNK)  // 98

// ---------------------------------------------------------------------------
// Detect index width of edge_index. int64 -> all high words zero (ids <100000).
// flag = 1 -> int64, flag = 0 -> int32.
__global__ void k_detect(const unsigned* ei, int* flag) {
  __shared__ int s_any;
  if (threadIdx.x == 0) s_any = 0;
  __syncthreads();
  int local = 0;
  for (int i = threadIdx.x; i < 4096; i += blockDim.x)
    if (ei[2 * i + 1] != 0u) local = 1;
  if (local) atomicOr(&s_any, 1);
  __syncthreads();
  if (threadIdx.x == 0) *flag = (s_any ? 0 : 1);
}

__device__ __forceinline__ int load_idx(const void* ei, int is64, size_t pos) {
  if (is64) return (int)((const long long*)ei)[pos];
  return ((const int*)ei)[pos];
}

// ---------------------------------------------------------------------------
// Integer in-degree histogram over dst.
__global__ void k_count(const void* __restrict__ ei, const int* __restrict__ flag,
                        int* __restrict__ cnt) {
  int e = blockIdx.x * blockDim.x + threadIdx.x;
  if (e >= N_EDGES) return;
  int dst = load_idx(ei, *flag, (size_t)N_EDGES + e);
  if ((unsigned)dst < N_NODES) atomicAdd(&cnt[dst], 1);
}

// dinv[i] = rsqrt(cnt[i] + 1)  (self-loop), one Newton refinement.
__global__ void k_dinv(const int* __restrict__ cnt, float* __restrict__ dinv) {
  int i = blockIdx.x * blockDim.x + threadIdx.x;
  if (i >= N_NODES) return;
  float d = (float)cnt[i] + 1.0f;
  float y = rsqrtf(d);
  y = y * (1.5f - 0.5f * d * y * y);
  dinv[i] = y;
}

// ---------------------------------------------------------------------------
// Exclusive prefix scan of cnt -> off (3 phases).
__global__ void k_scan1(const int* __restrict__ cnt, int* __restrict__ excl,
                        int* __restrict__ blockSums) {
  __shared__ int waveSums[SCAN_BLOCK / 64];
  int t = threadIdx.x;
  int base = blockIdx.x * SCAN_CHUNK + t * SCAN_ITEMS;
  int v[SCAN_ITEMS];
  int s = 0;
#pragma unroll
  for (int k = 0; k < SCAN_ITEMS; ++k) {
    v[k] = (base + k < N_NODES) ? cnt[base + k] : 0;
    s += v[k];
  }
  int lane = t & 63, wv = t >> 6;
  int inc = s;
#pragma unroll
  for (int o = 1; o < 64; o <<= 1) {
    int u = __shfl_up(inc, o);
    if (lane >= o) inc += u;
  }
  if (lane == 63) waveSums[wv] = inc;
  __syncthreads();
  int waveBase = 0;
  for (int w = 0; w < wv; ++w) waveBase += waveSums[w];
  int run = waveBase + inc - s;
#pragma unroll
  for (int k = 0; k < SCAN_ITEMS; ++k) {
    if (base + k < N_NODES) excl[base + k] = run;
    run += v[k];
  }
  if (t == SCAN_BLOCK - 1) blockSums[blockIdx.x] = waveBase + inc;
}

__global__ void k_scan2(int* __restrict__ blockSums) {
  __shared__ int s[128];
  int t = threadIdx.x;
  int orig = (t < N_SCAN_BLOCKS) ? blockSums[t] : 0;
  s[t] = orig;
  __syncthreads();
  for (int o = 1; o < 128; o <<= 1) {
    int u = (t >= o) ? s[t - o] : 0;
    __syncthreads();
    s[t] += u;
    __syncthreads();
  }
  if (t < N_SCAN_BLOCKS) blockSums[t] = s[t] - orig;  // exclusive
}

__global__ void k_scan3(int* __restrict__ excl, const int* __restrict__ blockSums,
                        int* __restrict__ cur) {
  int i = blockIdx.x * blockDim.x + threadIdx.x;
  if (i >= N_NODES) return;
  int o = excl[i] + blockSums[i / SCAN_CHUNK];
  excl[i] = o;
  cur[i] = o;
}

// ---------------------------------------------------------------------------
// Scatter edges into dst-sorted CSR: perm[pos] = (src, dinv[src]*dinv[dst]).
__global__ void k_scatter(const void* __restrict__ ei, const int* __restrict__ flag,
                          const float* __restrict__ dinv, int* __restrict__ cur,
                          uint2* __restrict__ perm) {
  int e = blockIdx.x * blockDim.x + threadIdx.x;
  if (e >= N_EDGES) return;
  int is64 = *flag;
  int src = load_idx(ei, is64, e);
  int dst = load_idx(ei, is64, (size_t)N_EDGES + e);
  if ((unsigned)src >= N_NODES || (unsigned)dst >= N_NODES) return;
  float w = dinv[src] * dinv[dst];
  int pos = atomicAdd(&cur[dst], 1);
  perm[pos] = make_uint2((unsigned)src, __float_as_uint(w));
}

// ---------------------------------------------------------------------------
// h1_lin = x @ W1   (x: [N,128], W1: [128,4]).  One wave per node.
__global__ __launch_bounds__(256) void k_mm1(const float* __restrict__ x,
                                             const float* __restrict__ W1,
                                             float* __restrict__ h1) {
  int gid = blockIdx.x * blockDim.x + threadIdx.x;
  int node = gid >> 6;
  int lane = threadIdx.x & 63;
  if (node >= N_NODES) return;
  float2 v = ((const float2*)x)[(size_t)node * 64 + lane];
  float4 w0 = ((const float4*)W1)[2 * lane];
  float4 w1 = ((const float4*)W1)[2 * lane + 1];
  float a0 = v.x * w0.x + v.y * w1.x;
  float a1 = v.x * w0.y + v.y * w1.y;
  float a2 = v.x * w0.z + v.y * w1.z;
  float a3 = v.x * w0.w + v.y * w1.w;
#pragma unroll
  for (int off = 32; off > 0; off >>= 1) {
    a0 += __shfl_down(a0, off);
    a1 += __shfl_down(a1, off);
    a2 += __shfl_down(a2, off);
    a3 += __shfl_down(a3, off);
  }
  if (lane == 0) ((float4*)h1)[node] = make_float4(a0, a1, a2, a3);
}

// ---------------------------------------------------------------------------
// Atomic-free segmented reduction: one wave per node over its CSR segment.
template <int F>
__global__ __launch_bounds__(256) void k_seg(const int* __restrict__ off,
                                             const int* __restrict__ cnt,
                                             const uint2* __restrict__ perm,
                                             const float* __restrict__ h,
                                             float* __restrict__ agg) {
  int node = (blockIdx.x * blockDim.x + threadIdx.x) >> 6;
  int lane = threadIdx.x & 63;
  if (node >= N_NODES) return;
  int base = off[node], n = cnt[node];
  if (F == 4) {
    float a0 = 0, a1 = 0, a2 = 0, a3 = 0;
    for (int j = lane; j < n; j += 64) {
      uint2 p = perm[base + j];
      float w = __uint_as_float(p.y);
      float4 v = ((const float4*)h)[p.x];
      a0 += v.x * w; a1 += v.y * w; a2 += v.z * w; a3 += v.w * w;
    }
#pragma unroll
    for (int m = 32; m; m >>= 1) {
      a0 += __shfl_xor(a0, m); a1 += __shfl_xor(a1, m);
      a2 += __shfl_xor(a2, m); a3 += __shfl_xor(a3, m);
    }
    if (lane == 0) ((float4*)agg)[node] = make_float4(a0, a1, a2, a3);
  } else {
    float a0 = 0, a1 = 0;
    for (int j = lane; j < n; j += 64) {
      uint2 p = perm[base + j];
      float w = __uint_as_float(p.y);
      float2 v = ((const float2*)h)[p.x];
      a0 += v.x * w; a1 += v.y * w;
    }
#pragma unroll
    for (int m = 32; m; m >>= 1) {
      a0 += __shfl_xor(a0, m); a1 += __shfl_xor(a1, m);
    }
    if (lane == 0) ((float2*)agg)[node] = make_float2(a0, a1);
  }
}

// ---------------------------------------------------------------------------
// Fallback atomic aggregation (only used if ws too small for CSR).
template <int F>
__global__ void k_agg_atomic(const void* __restrict__ ei, const int* __restrict__ flag,
                             const float* __restrict__ dinv, const float* __restrict__ h,
                             float* __restrict__ agg) {
  int e = blockIdx.x * blockDim.x + threadIdx.x;
  if (e >= N_EDGES) return;
  int is64 = *flag;
  int src = load_idx(ei, is64, e);
  int dst = load_idx(ei, is64, (size_t)N_EDGES + e);
  if ((unsigned)src >= N_NODES || (unsigned)dst >= N_NODES) return;
  float w = dinv[src] * dinv[dst];
  if (F == 4) {
    float4 v = ((const float4*)h)[src];
    atomicAdd(&agg[4 * dst + 0], v.x * w);
    atomicAdd(&agg[4 * dst + 1], v.y * w);
    atomicAdd(&agg[4 * dst + 2], v.z * w);
    atomicAdd(&agg[4 * dst + 3], v.w * w);
  } else {
    float2 v = ((const float2*)h)[src];
    atomicAdd(&agg[2 * dst + 0], v.x * w);
    atomicAdd(&agg[2 * dst + 1], v.y * w);
  }
}

// ---------------------------------------------------------------------------
// Epilogues: hin = tanh(agg + dinv^2*h_prev + b); next = hin @ W.
__global__ void k_mm2(const float* __restrict__ ag1, const float* __restrict__ h1,
                      const float* __restrict__ dinv, const float* __restrict__ W2,
                      const float* __restrict__ b1, float* __restrict__ h2) {
  int i = blockIdx.x * blockDim.x + threadIdx.x;
  if (i >= N_NODES) return;
  float d2 = dinv[i] * dinv[i];
  float4 a = ((const float4*)ag1)[i];
  float4 hl = ((const float4*)h1)[i];
  float t0 = tanhf(a.x + d2 * hl.x + b1[0]);
  float t1 = tanhf(a.y + d2 * hl.y + b1[1]);
  float t2 = tanhf(a.z + d2 * hl.z + b1[2]);
  float t3 = tanhf(a.w + d2 * hl.w + b1[3]);
  float4 r;
  r.x = t0 * W2[0] + t1 * W2[4] + t2 * W2[8]  + t3 * W2[12];
  r.y = t0 * W2[1] + t1 * W2[5] + t2 * W2[9]  + t3 * W2[13];
  r.z = t0 * W2[2] + t1 * W2[6] + t2 * W2[10] + t3 * W2[14];
  r.w = t0 * W2[3] + t1 * W2[7] + t2 * W2[11] + t3 * W2[15];
  ((float4*)h2)[i] = r;
}

__global__ void k_mm3(const float* __restrict__ ag2, const float* __restrict__ h2,
                      const float* __restrict__ dinv, const float* __restrict__ W3,
                      const float* __restrict__ b2, float* __restrict__ h3) {
  int i = blockIdx.x * blockDim.x + threadIdx.x;
  if (i >= N_NODES) return;
  float d2 = dinv[i] * dinv[i];
  float4 a = ((const float4*)ag2)[i];
  float4 hl = ((const float4*)h2)[i];
  float t0 = tanhf(a.x + d2 * hl.x + b2[0]);
  float t1 = tanhf(a.y + d2 * hl.y + b2[1]);
  float t2 = tanhf(a.z + d2 * hl.z + b2[2]);
  float t3 = tanhf(a.w + d2 * hl.w + b2[3]);
  float2 r;
  r.x = t0 * W3[0] + t1 * W3[2] + t2 * W3[4] + t3 * W3[6];
  r.y = t0 * W3[1] + t1 * W3[3] + t2 * W3[5] + t3 * W3[7];
  ((float2*)h3)[i] = r;
}

__global__ void k_out(const float* __restrict__ ag3, const float* __restrict__ h3,
                      const float* __restrict__ dinv, const float* __restrict__ Wc,
                      const float* __restrict__ bc, const float* __restrict__ b3,
                      float* __restrict__ out) {
  int i = blockIdx.x * blockDim.x + threadIdx.x;
  if (i >= N_NODES) return;
  float d2 = dinv[i] * dinv[i];
  float2 a = ((const float2*)ag3)[i];
  float2 hl = ((const float2*)h3)[i];
  float t0 = tanhf(a.x + d2 * hl.x + b3[0]);
  float t1 = tanhf(a.y + d2 * hl.y + b3[1]);
#pragma unroll
  for (int c = 0; c < 10; ++c)
    out[(size_t)i * 10 + c] = t0 * Wc[c] + t1 * Wc[10 + c] + bc[c];
  out[(size_t)N_NODES * 10 + 2 * i + 0] = t0;
  out[(size_t)N_NODES * 10 + 2 * i + 1] = t1;
}

// ---------------------------------------------------------------------------
extern "C" void kernel_launch(void* const* d_in, const int* in_sizes, int n_in,
                              void* d_out, int out_size, void* d_ws, size_t ws_size,
                              hipStream_t stream) {
  const float* x  = (const float*)d_in[0];
  const void*  ei = d_in[1];
  const float* W1 = (const float*)d_in[2];
  const float* b1 = (const float*)d_in[3];
  const float* W2 = (const float*)d_in[4];
  const float* b2 = (const float*)d_in[5];
  const float* W3 = (const float*)d_in[6];
  const float* b3 = (const float*)d_in[7];
  const float* Wc = (const float*)d_in[8];
  const float* bc = (const float*)d_in[9];
  float* out = (float*)d_out;

  const size_t N = N_NODES;
  float* base = (float*)d_ws;
  float* dinv = base;                     // N
  int*   cnt  = (int*)(base + N);         // N
  int*   off  = (int*)(base + 2 * N);     // N
  int*   cur  = (int*)(base + 3 * N);     // N
  float* h1   = base + 4 * N;             // 4N
  float* h2   = base + 8 * N;             // 4N
  float* h3   = base + 12 * N;            // 2N
  float* ag1  = base + 14 * N;            // 4N
  float* ag2  = base + 18 * N;            // 4N
  float* ag3  = base + 22 * N;            // 2N
  int* blockSums = (int*)(base + 24 * N); // 128
  int* flag      = (int*)(base + 24 * N + 128);
  uint2* perm    = (uint2*)(base + 24 * N + 256);  // N_EDGES * 8B

  const size_t NEEDED = (size_t)(24 * N + 256) * 4 + (size_t)N_EDGES * 8;
  const int EB = N_EDGES / 256;            // edge-grid blocks
  const int NB = (N_NODES + 255) / 256;    // node-grid blocks

  k_detect<<<1, 256, 0, stream>>>((const unsigned*)ei, flag);
  hipMemsetAsync(cnt, 0, N * sizeof(int), stream);
  k_count<<<EB, 256, 0, stream>>>(ei, flag, cnt);
  k_dinv<<<NB, 256, 0, stream>>>(cnt, dinv);
  k_mm1<<<(N_NODES * 64) / 256, 256, 0, stream>>>(x, W1, h1);

  if (ws_size >= NEEDED) {
    k_scan1<<<N_SCAN_BLOCKS, SCAN_BLOCK, 0, stream>>>(cnt, off, blockSums);
    k_scan2<<<1, 128, 0, stream>>>(blockSums);
    k_scan3<<<NB, 256, 0, stream>>>(off, blockSums, cur);
    k_scatter<<<EB, 256, 0, stream>>>(ei, flag, dinv, cur, perm);

    const int SB = (N_NODES * 64) / 256;   // one wave per node
    k_seg<4><<<SB, 256, 0, stream>>>(off, cnt, perm, h1, ag1);
    k_mm2<<<NB, 256, 0, stream>>>(ag1, h1, dinv, W2, b1, h2);
    k_seg<4><<<SB, 256, 0, stream>>>(off, cnt, perm, h2, ag2);
    k_mm3<<<NB, 256, 0, stream>>>(ag2, h2, dinv, W3, b2, h3);
    k_seg<2><<<SB, 256, 0, stream>>>(off, cnt, perm, h3, ag3);
    k_out<<<NB, 256, 0, stream>>>(ag3, h3, dinv, Wc, bc, b3, out);
  } else {
    // Fallback: atomic aggregation (round-1 structure).
    hipMemsetAsync(ag1, 0, 10 * N * sizeof(float), stream);
    k_agg_atomic<4><<<EB, 256, 0, stream>>>(ei, flag, dinv, h1, ag1);
    k_mm2<<<NB, 256, 0, stream>>>(ag1, h1, dinv, W2, b1, h2);
    k_agg_atomic<4><<<EB, 256, 0, stream>>>(ei, flag, dinv, h2, ag2);
    k_mm3<<<NB, 256, 0, stream>>>(ag2, h2, dinv, W3, b2, h3);
    k_agg_atomic<2><<<EB, 256, 0, stream>>>(ei, flag, dinv, h3, ag3);
    k_out<<<NB, 256, 0, stream>>>(ag3, h3, dinv, Wc, bc, b3, out);
  }
}

// Round 3
// 686.081 us; speedup vs baseline: 5.2973x; 1.1699x over previous
//
#include <hip/hip_runtime.h>
#include <hip/hip_bf16.h>
#include <stdint.h>

#define N_NODES 100000
#define N_EDGES 6400000

#define NPB 128                                   // nodes per bucket (dstLocal = dst & 127)
#define NBKT ((N_NODES + NPB - 1) / NPB)          // 782 buckets
#define CAP 12288                                 // per-bucket record capacity (mean 8188, ~45 sigma)
#define BIN_CHUNK 8192
#define NBIN_BLOCKS ((N_EDGES + BIN_CHUNK - 1) / BIN_CHUNK)  // 782

// ---------------------------------------------------------------------------
// Detect index width of edge_index. int64 -> all high words zero (ids <100000).
// flag = 1 -> int64, flag = 0 -> int32.
__global__ void k_detect(const unsigned* ei, int* flag) {
  __shared__ int s_any;
  if (threadIdx.x == 0) s_any = 0;
  __syncthreads();
  int local = 0;
  for (int i = threadIdx.x; i < 4096; i += blockDim.x)
    if (ei[2 * i + 1] != 0u) local = 1;
  if (local) atomicOr(&s_any, 1);
  __syncthreads();
  if (threadIdx.x == 0) *flag = (s_any ? 0 : 1);
}

__device__ __forceinline__ int load_idx(const void* ei, int is64, size_t pos) {
  if (is64) return (int)((const long long*)ei)[pos];
  return ((const int*)ei)[pos];
}

// ---------------------------------------------------------------------------
// Bucket-binning: per block, LDS histogram -> one global reservation per
// (block,bucket) -> placement. Record = src | (dstLocal << 17), 4 bytes.
__global__ __launch_bounds__(256) void k_bin(const void* __restrict__ ei,
                                             const int* __restrict__ flag,
                                             int* __restrict__ gcur,
                                             unsigned* __restrict__ perm) {
  __shared__ int lcnt[NBKT];
  __shared__ int lcur[NBKT];
  int t = threadIdx.x;
  for (int i = t; i < NBKT; i += 256) lcnt[i] = 0;
  __syncthreads();
  int is64 = *flag;
  size_t e0 = (size_t)blockIdx.x * BIN_CHUNK;
  int n = (int)((e0 + BIN_CHUNK <= N_EDGES) ? BIN_CHUNK : (N_EDGES - e0));

  // phase 1: count valid edges per bucket
  for (int k = t; k < n; k += 256) {
    int src = load_idx(ei, is64, e0 + k);
    int dst = load_idx(ei, is64, (size_t)N_EDGES + e0 + k);
    if ((unsigned)src < N_NODES && (unsigned)dst < N_NODES)
      atomicAdd(&lcnt[dst >> 7], 1);
  }
  __syncthreads();

  // phase 2: reserve global space per bucket
  for (int b = t; b < NBKT; b += 256) {
    int c = lcnt[b];
    int gb = 0;
    if (c) gb = atomicAdd(&gcur[b], c);
    lcur[b] = b * CAP + gb;
  }
  __syncthreads();

  // phase 3: place records (chunk re-read is L2-resident)
  for (int k = t; k < n; k += 256) {
    int src = load_idx(ei, is64, e0 + k);
    int dst = load_idx(ei, is64, (size_t)N_EDGES + e0 + k);
    if ((unsigned)src >= N_NODES || (unsigned)dst >= N_NODES) continue;
    int b = dst >> 7;
    int idx = atomicAdd(&lcur[b], 1);
    if (idx < (b + 1) * CAP)
      perm[idx] = (unsigned)src | ((unsigned)(dst & (NPB - 1)) << 17);
  }
}

// ---------------------------------------------------------------------------
// Degree from binned records (atomic-free globally): dinv = rsqrt(deg+1).
__global__ __launch_bounds__(256) void k_bdeg(const int* __restrict__ gcur,
                                              const unsigned* __restrict__ perm,
                                              float* __restrict__ dinv) {
  __shared__ int dacc[NPB];
  int t = threadIdx.x, b = blockIdx.x;
  if (t < NPB) dacc[t] = 0;
  __syncthreads();
  int cnt = min(gcur[b], CAP);
  int base = b * CAP;
  for (int j = t; j < cnt; j += 256) atomicAdd(&dacc[perm[base + j] >> 17], 1);
  __syncthreads();
  if (t < NPB) {
    int node = b * NPB + t;
    if (node < N_NODES) {
      float d = (float)dacc[t] + 1.0f;
      float y = rsqrtf(d);
      y = y * (1.5f - 0.5f * d * y * y);
      dinv[node] = y;
    }
  }
}

// ---------------------------------------------------------------------------
// hs1 = dinv * (x @ W1)   (x: [N,128], W1: [128,4]).  One wave per node.
__global__ __launch_bounds__(256) void k_mm1(const float* __restrict__ x,
                                             const float* __restrict__ W1,
                                             const float* __restrict__ dinv,
                                             float* __restrict__ hs1) {
  int gid = blockIdx.x * blockDim.x + threadIdx.x;
  int node = gid >> 6;
  int lane = threadIdx.x & 63;
  if (node >= N_NODES) return;
  float2 v = ((const float2*)x)[(size_t)node * 64 + lane];
  float4 w0 = ((const float4*)W1)[2 * lane];
  float4 w1 = ((const float4*)W1)[2 * lane + 1];
  float a0 = v.x * w0.x + v.y * w1.x;
  float a1 = v.x * w0.y + v.y * w1.y;
  float a2 = v.x * w0.z + v.y * w1.z;
  float a3 = v.x * w0.w + v.y * w1.w;
#pragma unroll
  for (int off = 32; off > 0; off >>= 1) {
    a0 += __shfl_down(a0, off);
    a1 += __shfl_down(a1, off);
    a2 += __shfl_down(a2, off);
    a3 += __shfl_down(a3, off);
  }
  if (lane == 0) {
    float d = dinv[node];
    ((float4*)hs1)[node] = make_float4(d * a0, d * a1, d * a2, d * a3);
  }
}

// ---------------------------------------------------------------------------
// Layer 1: acc = sum_{edges} hs1[src] per dst (LDS accumulate), then
// hin = tanh(dinv*(acc + hs1[n]) + b1); hs2 = dinv * (hin @ W2).
__global__ __launch_bounds__(256) void k_lagg1(const int* __restrict__ gcur,
                                               const unsigned* __restrict__ perm,
                                               const float* __restrict__ hs1,
                                               const float* __restrict__ dinv,
                                               const float* __restrict__ W2,
                                               const float* __restrict__ b1,
                                               float* __restrict__ hs2) {
  __shared__ float acc[NPB * 4];
  int t = threadIdx.x, b = blockIdx.x;
  for (int i = t; i < NPB * 4; i += 256) acc[i] = 0.0f;
  __syncthreads();
  int cnt = min(gcur[b], CAP);
  int base = b * CAP;
  for (int j = t; j < cnt; j += 256) {
    unsigned r = perm[base + j];
    int src = r & 0x1FFFF;
    int dl = r >> 17;
    float4 v = ((const float4*)hs1)[src];
    atomicAdd(&acc[dl * 4 + 0], v.x);
    atomicAdd(&acc[dl * 4 + 1], v.y);
    atomicAdd(&acc[dl * 4 + 2], v.z);
    atomicAdd(&acc[dl * 4 + 3], v.w);
  }
  __syncthreads();
  if (t < NPB) {
    int node = b * NPB + t;
    if (node < N_NODES) {
      float d = dinv[node];
      float4 hl = ((const float4*)hs1)[node];
      float t0 = tanhf(d * (acc[t * 4 + 0] + hl.x) + b1[0]);
      float t1 = tanhf(d * (acc[t * 4 + 1] + hl.y) + b1[1]);
      float t2 = tanhf(d * (acc[t * 4 + 2] + hl.z) + b1[2]);
      float t3 = tanhf(d * (acc[t * 4 + 3] + hl.w) + b1[3]);
      float4 r;
      r.x = d * (t0 * W2[0] + t1 * W2[4] + t2 * W2[8]  + t3 * W2[12]);
      r.y = d * (t0 * W2[1] + t1 * W2[5] + t2 * W2[9]  + t3 * W2[13]);
      r.z = d * (t0 * W2[2] + t1 * W2[6] + t2 * W2[10] + t3 * W2[14]);
      r.w = d * (t0 * W2[3] + t1 * W2[7] + t2 * W2[11] + t3 * W2[15]);
      ((float4*)hs2)[node] = r;
    }
  }
}

// Layer 2: same with W3 [4,2]; hs3 = dinv * (hin @ W3).
__global__ __launch_bounds__(256) void k_lagg2(const int* __restrict__ gcur,
                                               const unsigned* __restrict__ perm,
                                               const float* __restrict__ hs2,
                                               const float* __restrict__ dinv,
                                               const float* __restrict__ W3,
                                               const float* __restrict__ b2,
                                               float* __restrict__ hs3) {
  __shared__ float acc[NPB * 4];
  int t = threadIdx.x, b = blockIdx.x;
  for (int i = t; i < NPB * 4; i += 256) acc[i] = 0.0f;
  __syncthreads();
  int cnt = min(gcur[b], CAP);
  int base = b * CAP;
  for (int j = t; j < cnt; j += 256) {
    unsigned r = perm[base + j];
    int src = r & 0x1FFFF;
    int dl = r >> 17;
    float4 v = ((const float4*)hs2)[src];
    atomicAdd(&acc[dl * 4 + 0], v.x);
    atomicAdd(&acc[dl * 4 + 1], v.y);
    atomicAdd(&acc[dl * 4 + 2], v.z);
    atomicAdd(&acc[dl * 4 + 3], v.w);
  }
  __syncthreads();
  if (t < NPB) {
    int node = b * NPB + t;
    if (node < N_NODES) {
      float d = dinv[node];
      float4 hl = ((const float4*)hs2)[node];
      float t0 = tanhf(d * (acc[t * 4 + 0] + hl.x) + b2[0]);
      float t1 = tanhf(d * (acc[t * 4 + 1] + hl.y) + b2[1]);
      float t2 = tanhf(d * (acc[t * 4 + 2] + hl.z) + b2[2]);
      float t3 = tanhf(d * (acc[t * 4 + 3] + hl.w) + b2[3]);
      float2 r;
      r.x = d * (t0 * W3[0] + t1 * W3[2] + t2 * W3[4] + t3 * W3[6]);
      r.y = d * (t0 * W3[1] + t1 * W3[3] + t2 * W3[5] + t3 * W3[7]);
      ((float2*)hs3)[node] = r;
    }
  }
}

// Layer 3 (final): h = tanh(dinv*(acc + hs3[n]) + b3); out = h@Wc + bc, plus h.
__global__ __launch_bounds__(256) void k_lagg3(const int* __restrict__ gcur,
                                               const unsigned* __restrict__ perm,
                                               const float* __restrict__ hs3,
                                               const float* __restrict__ dinv,
                                               const float* __restrict__ Wc,
                                               const float* __restrict__ bc,
                                               const float* __restrict__ b3,
                                               float* __restrict__ out) {
  __shared__ float acc[NPB * 2];
  int t = threadIdx.x, b = blockIdx.x;
  for (int i = t; i < NPB * 2; i += 256) acc[i] = 0.0f;
  __syncthreads();
  int cnt = min(gcur[b], CAP);
  int base = b * CAP;
  for (int j = t; j < cnt; j += 256) {
    unsigned r = perm[base + j];
    int src = r & 0x1FFFF;
    int dl = r >> 17;
    float2 v = ((const float2*)hs3)[src];
    atomicAdd(&acc[dl * 2 + 0], v.x);
    atomicAdd(&acc[dl * 2 + 1], v.y);
  }
  __syncthreads();
  if (t < NPB) {
    int node = b * NPB + t;
    if (node < N_NODES) {
      float d = dinv[node];
      float2 hl = ((const float2*)hs3)[node];
      float t0 = tanhf(d * (acc[t * 2 + 0] + hl.x) + b3[0]);
      float t1 = tanhf(d * (acc[t * 2 + 1] + hl.y) + b3[1]);
#pragma unroll
      for (int c = 0; c < 10; ++c)
        out[(size_t)node * 10 + c] = t0 * Wc[c] + t1 * Wc[10 + c] + bc[c];
      out[(size_t)N_NODES * 10 + 2 * node + 0] = t0;
      out[(size_t)N_NODES * 10 + 2 * node + 1] = t1;
    }
  }
}

// ---------------------------------------------------------------------------
extern "C" void kernel_launch(void* const* d_in, const int* in_sizes, int n_in,
                              void* d_out, int out_size, void* d_ws, size_t ws_size,
                              hipStream_t stream) {
  const float* x  = (const float*)d_in[0];
  const void*  ei = d_in[1];
  const float* W1 = (const float*)d_in[2];
  const float* b1 = (const float*)d_in[3];
  const float* W2 = (const float*)d_in[4];
  const float* b2 = (const float*)d_in[5];
  const float* W3 = (const float*)d_in[6];
  const float* b3 = (const float*)d_in[7];
  const float* Wc = (const float*)d_in[8];
  const float* bc = (const float*)d_in[9];
  float* out = (float*)d_out;

  const size_t N = N_NODES;
  float* base = (float*)d_ws;
  float* dinv = base;                       // N
  float* hs1  = base + N;                   // 4N (16B aligned: N*4 % 16 == 0)
  float* hs2  = base + 5 * N;               // 4N
  float* hs3  = base + 9 * N;               // 2N
  int*   gcur = (int*)(base + 11 * N);      // NBKT
  int*   flag = (int*)(base + 11 * N + 1024);
  unsigned* perm = (unsigned*)(base + 11 * N + 2048);  // NBKT*CAP u32 = 38.4MB

  k_detect<<<1, 256, 0, stream>>>((const unsigned*)ei, flag);
  hipMemsetAsync(gcur, 0, NBKT * sizeof(int), stream);
  k_bin<<<NBIN_BLOCKS, 256, 0, stream>>>(ei, flag, gcur, perm);
  k_bdeg<<<NBKT, 256, 0, stream>>>(gcur, perm, dinv);
  k_mm1<<<(N_NODES * 64) / 256, 256, 0, stream>>>(x, W1, dinv, hs1);
  k_lagg1<<<NBKT, 256, 0, stream>>>(gcur, perm, hs1, dinv, W2, b1, hs2);
  k_lagg2<<<NBKT, 256, 0, stream>>>(gcur, perm, hs2, dinv, W3, b2, hs3);
  k_lagg3<<<NBKT, 256, 0, stream>>>(gcur, perm, hs3, dinv, Wc, bc, b3, out);
}

// Round 4
// 662.325 us; speedup vs baseline: 5.4873x; 1.0359x over previous
//
#include <hip/hip_runtime.h>
#include <hip/hip_bf16.h>
#include <stdint.h>

#define N_NODES 100000
#define N_EDGES 6400000

#define NPB 128                                   // nodes per bucket (dstLocal = dst & 127)
#define NBKT ((N_NODES + NPB - 1) / NPB)          // 782 buckets
#define CAP 12288                                 // per-bucket record capacity (mean 8188)
#define SPLIT 8                                   // blocks per bucket in aggregation
#define BIN_CHUNK 8192
#define NBIN_BLOCKS ((N_EDGES + BIN_CHUNK - 1) / BIN_CHUNK)  // 782
#define PART_ELEMS ((size_t)NBKT * SPLIT * NPB * 4)          // partial buffer (F=4 worst case)

// ---------------------------------------------------------------------------
// Detect index width of edge_index. int64 -> all high words zero (ids <100000).
__global__ void k_detect(const unsigned* ei, int* flag) {
  __shared__ int s_any;
  if (threadIdx.x == 0) s_any = 0;
  __syncthreads();
  int local = 0;
  for (int i = threadIdx.x; i < 4096; i += blockDim.x)
    if (ei[2 * i + 1] != 0u) local = 1;
  if (local) atomicOr(&s_any, 1);
  __syncthreads();
  if (threadIdx.x == 0) *flag = (s_any ? 0 : 1);
}

__device__ __forceinline__ int load_idx(const void* ei, int is64, size_t pos) {
  if (is64) return (int)((const long long*)ei)[pos];
  return ((const int*)ei)[pos];
}

// ---------------------------------------------------------------------------
// Bucket-binning: per block, LDS histogram -> one global reservation per
// (block,bucket) -> placement. Record = src | (dstLocal << 17), 4 bytes.
__global__ __launch_bounds__(256) void k_bin(const void* __restrict__ ei,
                                             const int* __restrict__ flag,
                                             int* __restrict__ gcur,
                                             unsigned* __restrict__ perm) {
  __shared__ int lcnt[NBKT];
  __shared__ int lcur[NBKT];
  int t = threadIdx.x;
  for (int i = t; i < NBKT; i += 256) lcnt[i] = 0;
  __syncthreads();
  int is64 = *flag;
  size_t e0 = (size_t)blockIdx.x * BIN_CHUNK;
  int n = (int)((e0 + BIN_CHUNK <= N_EDGES) ? BIN_CHUNK : (N_EDGES - e0));

  for (int k = t; k < n; k += 256) {
    int src = load_idx(ei, is64, e0 + k);
    int dst = load_idx(ei, is64, (size_t)N_EDGES + e0 + k);
    if ((unsigned)src < N_NODES && (unsigned)dst < N_NODES)
      atomicAdd(&lcnt[dst >> 7], 1);
  }
  __syncthreads();

  for (int b = t; b < NBKT; b += 256) {
    int c = lcnt[b];
    int gb = 0;
    if (c) gb = atomicAdd(&gcur[b], c);
    lcur[b] = b * CAP + gb;
  }
  __syncthreads();

  for (int k = t; k < n; k += 256) {
    int src = load_idx(ei, is64, e0 + k);
    int dst = load_idx(ei, is64, (size_t)N_EDGES + e0 + k);
    if ((unsigned)src >= N_NODES || (unsigned)dst >= N_NODES) continue;
    int b = dst >> 7;
    int idx = atomicAdd(&lcur[b], 1);
    if (idx < (b + 1) * CAP)
      perm[idx] = (unsigned)src | ((unsigned)(dst & (NPB - 1)) << 17);
  }
}

// ---------------------------------------------------------------------------
// Degree from binned records, split SPLIT-ways per bucket, combine via
// global int atomics (800k total).
__global__ __launch_bounds__(256) void k_bdeg(const int* __restrict__ gcur,
                                              const unsigned* __restrict__ perm,
                                              int* __restrict__ deg) {
  __shared__ int dacc[NPB];
  int t = threadIdx.x, b = blockIdx.x / SPLIT, s = blockIdx.x % SPLIT;
  if (t < NPB) dacc[t] = 0;
  __syncthreads();
  int cnt = min(gcur[b], CAP);
  int seg = (cnt + SPLIT - 1) / SPLIT;
  int lo = s * seg;
  int hi = min(cnt, lo + seg);
  int base = b * CAP;
  for (int j = lo + t; j < hi; j += 256) atomicAdd(&dacc[perm[base + j] >> 17], 1);
  __syncthreads();
  if (t < NPB) {
    int v = dacc[t];
    if (v) atomicAdd(&deg[b * NPB + t], v);
  }
}

// dinv[i] = rsqrt(deg[i] + 1)  (self-loop), one Newton refinement.
__global__ void k_dinv(const int* __restrict__ deg, float* __restrict__ dinv) {
  int i = blockIdx.x * blockDim.x + threadIdx.x;
  if (i >= N_NODES) return;
  float d = (float)deg[i] + 1.0f;
  float y = rsqrtf(d);
  y = y * (1.5f - 0.5f * d * y * y);
  dinv[i] = y;
}

// ---------------------------------------------------------------------------
// hs1 = dinv * (x @ W1)   (x: [N,128], W1: [128,4]).  One wave per node.
__global__ __launch_bounds__(256) void k_mm1(const float* __restrict__ x,
                                             const float* __restrict__ W1,
                                             const float* __restrict__ dinv,
                                             float* __restrict__ hs1) {
  int gid = blockIdx.x * blockDim.x + threadIdx.x;
  int node = gid >> 6;
  int lane = threadIdx.x & 63;
  if (node >= N_NODES) return;
  float2 v = ((const float2*)x)[(size_t)node * 64 + lane];
  float4 w0 = ((const float4*)W1)[2 * lane];
  float4 w1 = ((const float4*)W1)[2 * lane + 1];
  float a0 = v.x * w0.x + v.y * w1.x;
  float a1 = v.x * w0.y + v.y * w1.y;
  float a2 = v.x * w0.z + v.y * w1.z;
  float a3 = v.x * w0.w + v.y * w1.w;
#pragma unroll
  for (int off = 32; off > 0; off >>= 1) {
    a0 += __shfl_down(a0, off);
    a1 += __shfl_down(a1, off);
    a2 += __shfl_down(a2, off);
    a3 += __shfl_down(a3, off);
  }
  if (lane == 0) {
    float d = dinv[node];
    ((float4*)hs1)[node] = make_float4(d * a0, d * a1, d * a2, d * a3);
  }
}

// ---------------------------------------------------------------------------
// Partial aggregation: block = (bucket b, split s). 4-way ILP gathers, LDS
// accumulate, write private partial (no global atomics).
template <int F>
__global__ __launch_bounds__(256) void k_part(const int* __restrict__ gcur,
                                              const unsigned* __restrict__ perm,
                                              const float* __restrict__ hs,
                                              float* __restrict__ partial) {
  __shared__ float acc[NPB * F];
  int t = threadIdx.x, b = blockIdx.x / SPLIT, s = blockIdx.x % SPLIT;
  for (int i = t; i < NPB * F; i += 256) acc[i] = 0.0f;
  __syncthreads();
  int cnt = min(gcur[b], CAP);
  int seg = (cnt + SPLIT - 1) / SPLIT;
  int lo = s * seg;
  int hi = min(cnt, lo + seg);
  int base = b * CAP;
  for (int j0 = lo; j0 < hi; j0 += 1024) {
    unsigned r[4];
    bool val[4];
#pragma unroll
    for (int k = 0; k < 4; ++k) {
      int idx = j0 + t + k * 256;
      val[k] = idx < hi;
      r[k] = val[k] ? perm[base + idx] : 0u;
    }
    float4 v4[4];
    float2 v2[4];
#pragma unroll
    for (int k = 0; k < 4; ++k) {
      if (F == 4) v4[k] = val[k] ? ((const float4*)hs)[r[k] & 0x1FFFF]
                                 : make_float4(0, 0, 0, 0);
      else        v2[k] = val[k] ? ((const float2*)hs)[r[k] & 0x1FFFF]
                                 : make_float2(0, 0);
    }
#pragma unroll
    for (int k = 0; k < 4; ++k) {
      if (!val[k]) continue;
      int dl = (int)(r[k] >> 17);
      if (F == 4) {
        atomicAdd(&acc[dl * 4 + 0], v4[k].x);
        atomicAdd(&acc[dl * 4 + 1], v4[k].y);
        atomicAdd(&acc[dl * 4 + 2], v4[k].z);
        atomicAdd(&acc[dl * 4 + 3], v4[k].w);
      } else {
        atomicAdd(&acc[dl * 2 + 0], v2[k].x);
        atomicAdd(&acc[dl * 2 + 1], v2[k].y);
      }
    }
  }
  __syncthreads();
  size_t pb = (size_t)(b * SPLIT + s) * (NPB * F);
  for (int i = t; i < NPB * F; i += 256) partial[pb + i] = acc[i];
}

// ---------------------------------------------------------------------------
// Reduce SPLIT partials + fused epilogue per layer.
__global__ void k_red1(const float* __restrict__ partial, const float* __restrict__ hs1,
                       const float* __restrict__ dinv, const float* __restrict__ W2,
                       const float* __restrict__ b1, float* __restrict__ hs2) {
  int node = blockIdx.x * blockDim.x + threadIdx.x;
  if (node >= N_NODES) return;
  int b = node >> 7, t = node & (NPB - 1);
  float a0 = 0, a1 = 0, a2 = 0, a3 = 0;
#pragma unroll
  for (int s = 0; s < SPLIT; ++s) {
    float4 p = ((const float4*)partial)[(size_t)(b * SPLIT + s) * NPB + t];
    a0 += p.x; a1 += p.y; a2 += p.z; a3 += p.w;
  }
  float d = dinv[node];
  float4 hl = ((const float4*)hs1)[node];
  float t0 = tanhf(d * (a0 + hl.x) + b1[0]);
  float t1 = tanhf(d * (a1 + hl.y) + b1[1]);
  float t2 = tanhf(d * (a2 + hl.z) + b1[2]);
  float t3 = tanhf(d * (a3 + hl.w) + b1[3]);
  float4 r;
  r.x = d * (t0 * W2[0] + t1 * W2[4] + t2 * W2[8]  + t3 * W2[12]);
  r.y = d * (t0 * W2[1] + t1 * W2[5] + t2 * W2[9]  + t3 * W2[13]);
  r.z = d * (t0 * W2[2] + t1 * W2[6] + t2 * W2[10] + t3 * W2[14]);
  r.w = d * (t0 * W2[3] + t1 * W2[7] + t2 * W2[11] + t3 * W2[15]);
  ((float4*)hs2)[node] = r;
}

__global__ void k_red2(const float* __restrict__ partial, const float* __restrict__ hs2,
                       const float* __restrict__ dinv, const float* __restrict__ W3,
                       const float* __restrict__ b2, float* __restrict__ hs3) {
  int node = blockIdx.x * blockDim.x + threadIdx.x;
  if (node >= N_NODES) return;
  int b = node >> 7, t = node & (NPB - 1);
  float a0 = 0, a1 = 0, a2 = 0, a3 = 0;
#pragma unroll
  for (int s = 0; s < SPLIT; ++s) {
    float4 p = ((const float4*)partial)[(size_t)(b * SPLIT + s) * NPB + t];
    a0 += p.x; a1 += p.y; a2 += p.z; a3 += p.w;
  }
  float d = dinv[node];
  float4 hl = ((const float4*)hs2)[node];
  float t0 = tanhf(d * (a0 + hl.x) + b2[0]);
  float t1 = tanhf(d * (a1 + hl.y) + b2[1]);
  float t2 = tanhf(d * (a2 + hl.z) + b2[2]);
  float t3 = tanhf(d * (a3 + hl.w) + b2[3]);
  float2 r;
  r.x = d * (t0 * W3[0] + t1 * W3[2] + t2 * W3[4] + t3 * W3[6]);
  r.y = d * (t0 * W3[1] + t1 * W3[3] + t2 * W3[5] + t3 * W3[7]);
  ((float2*)hs3)[node] = r;
}

__global__ void k_red3(const float* __restrict__ partial, const float* __restrict__ hs3,
                       const float* __restrict__ dinv, const float* __restrict__ Wc,
                       const float* __restrict__ bc, const float* __restrict__ b3,
                       float* __restrict__ out) {
  int node = blockIdx.x * blockDim.x + threadIdx.x;
  if (node >= N_NODES) return;
  int b = node >> 7, t = node & (NPB - 1);
  float a0 = 0, a1 = 0;
#pragma unroll
  for (int s = 0; s < SPLIT; ++s) {
    float2 p = ((const float2*)partial)[(size_t)(b * SPLIT + s) * NPB + t];
    a0 += p.x; a1 += p.y;
  }
  float d = dinv[node];
  float2 hl = ((const float2*)hs3)[node];
  float t0 = tanhf(d * (a0 + hl.x) + b3[0]);
  float t1 = tanhf(d * (a1 + hl.y) + b3[1]);
#pragma unroll
  for (int c = 0; c < 10; ++c)
    out[(size_t)node * 10 + c] = t0 * Wc[c] + t1 * Wc[10 + c] + bc[c];
  out[(size_t)N_NODES * 10 + 2 * node + 0] = t0;
  out[(size_t)N_NODES * 10 + 2 * node + 1] = t1;
}

// ---------------------------------------------------------------------------
extern "C" void kernel_launch(void* const* d_in, const int* in_sizes, int n_in,
                              void* d_out, int out_size, void* d_ws, size_t ws_size,
                              hipStream_t stream) {
  const float* x  = (const float*)d_in[0];
  const void*  ei = d_in[1];
  const float* W1 = (const float*)d_in[2];
  const float* b1 = (const float*)d_in[3];
  const float* W2 = (const float*)d_in[4];
  const float* b2 = (const float*)d_in[5];
  const float* W3 = (const float*)d_in[6];
  const float* b3 = (const float*)d_in[7];
  const float* Wc = (const float*)d_in[8];
  const float* bc = (const float*)d_in[9];
  float* out = (float*)d_out;

  const size_t N = N_NODES;
  float* base = (float*)d_ws;
  float* dinv = base;                            // N
  float* hs1  = base + N;                        // 4N
  float* hs2  = base + 5 * N;                    // 4N
  float* hs3  = base + 9 * N;                    // 2N
  int*   degi = (int*)(base + 11 * N);           // N  (zeroed with gcur)
  int*   gcur = (int*)(base + 12 * N);           // 1024
  int*   flag = (int*)(base + 12 * N + 1024);    // 16B slot
  float* partial = base + 12 * N + 2048;         // PART_ELEMS floats (12.8 MB)
  unsigned* perm = (unsigned*)(partial + PART_ELEMS);  // NBKT*CAP u32 (38.4 MB)

  const int NB = (N_NODES + 255) / 256;

  k_detect<<<1, 256, 0, stream>>>((const unsigned*)ei, flag);
  hipMemsetAsync(degi, 0, (N + 1024) * sizeof(int), stream);
  k_bin<<<NBIN_BLOCKS, 256, 0, stream>>>(ei, flag, gcur, perm);
  k_bdeg<<<NBKT * SPLIT, 256, 0, stream>>>(gcur, perm, degi);
  k_dinv<<<NB, 256, 0, stream>>>(degi, dinv);
  k_mm1<<<(N_NODES * 64) / 256, 256, 0, stream>>>(x, W1, dinv, hs1);

  k_part<4><<<NBKT * SPLIT, 256, 0, stream>>>(gcur, perm, hs1, partial);
  k_red1<<<NB, 256, 0, stream>>>(partial, hs1, dinv, W2, b1, hs2);
  k_part<4><<<NBKT * SPLIT, 256, 0, stream>>>(gcur, perm, hs2, partial);
  k_red2<<<NB, 256, 0, stream>>>(partial, hs2, dinv, W3, b2, hs3);
  k_part<2><<<NBKT * SPLIT, 256, 0, stream>>>(gcur, perm, hs3, partial);
  k_red3<<<NB, 256, 0, stream>>>(partial, hs3, dinv, Wc, bc, b3, out);
}